// Round 12
// baseline (203.610 us; speedup 1.0000x reference)
//
#include <hip/hip_runtime.h>
#include <cmath>

#define TPB 256

static const int NTOK  = 1025;
static const int DIM   = 768;
static const int HEADS = 12;
static const int QK3   = 2304;
static const int ROWS  = 4 * NTOK;        // 4100
static const int MROWS = 4 * (NTOK - 1);  // 4096
static const int MPAD  = 4224;            // 33*128 padded A rows
static const int NPAD  = 1088;            // 17*64
static const size_t OUT0 = (size_t)ROWS * DIM;
static const size_t APLANE = (size_t)MPAD * DIM;   // bf16 per plane

// workspace offsets in floats (qkv/qkvm bf16)
static const size_t OFF_QKV16  = 0;          // 4100*2304 u16 = 4,723,200 f
static const size_t OFF_QKVM16 = 4800000;    // 4096*2304 u16 = 4,718,592 f
static const size_t OFF_QE     = 9600000;    // 48*1088*64 u16 = 1,671,168 f
static const size_t OFF_KF     = 11300000;   // 48*17*8*512 u16 = 1,671,168 f (frag-major K)
static const size_t OFF_VF     = 13000000;   // 48*17*16*512 u16 = 3,342,336 f (frag-major V^T)
static const size_t OFF_ABF    = 16400000;   // 2*4224*768 u16 = 3,244,032 f
static const size_t OFF_WQ     = 19700000;   // 2*2304*768 u16 = 1,769,472 f
static const size_t OFF_WO     = 21500000;   // 2*768*768 u16  =   589,824 f
static const size_t OFF_CMAX   = 22100000;   // 9,216 f
static const size_t OFF_UPD    = 22110000;   // 4,100 f

typedef __attribute__((ext_vector_type(8))) short short8;
typedef __attribute__((ext_vector_type(4))) float f32x4;

__device__ __forceinline__ unsigned short f2bf(float f) {
    union { float f; unsigned int u; } c; c.f = f;
    unsigned int u = c.u + 0x7fffu + ((c.u >> 16) & 1u);  // RNE
    return (unsigned short)(u >> 16);
}
__device__ __forceinline__ float bf2f(unsigned short u) {
    union { unsigned int u; float f; } c; c.u = (unsigned int)u << 16;
    return c.f;
}
// packed f32x2 -> bf16x2 in ONE instruction (RNE)
__device__ __forceinline__ unsigned int cvtpk(float a, float b) {
    unsigned int r;
    asm("v_cvt_pk_bf16_f32 %0, %1, %2" : "=v"(r) : "v"(a), "v"(b));
    return r;
}
__device__ __forceinline__ void gl_lds16(const unsigned short* g, unsigned short* l) {
    __builtin_amdgcn_global_load_lds(
        (const __attribute__((address_space(1))) unsigned int*)g,
        (__attribute__((address_space(3))) unsigned int*)l, 16, 0, 0);
}

// ---------------------------------------------------------------------------
// K0: fp32 -> bf16 conversions (cvtpk version).
// upd flags fused into z=1; z=4: bx==0 CLS upd rows, bx 1..9 cmax zero.
// ---------------------------------------------------------------------------
__global__ __launch_bounds__(TPB)
void k_cvt(const float* __restrict__ x, const float* __restrict__ mask,
           const float* __restrict__ wqkv, const float* __restrict__ wout,
           unsigned short* __restrict__ Abf, unsigned short* __restrict__ Wq,
           unsigned short* __restrict__ Wo, float* __restrict__ upd,
           float* __restrict__ cmax)
{
    const int z = blockIdx.z;
    if (z == 4) {
        const int bx = blockIdx.x;
        if (bx == 0) {
            if (threadIdx.x < 4) upd[threadIdx.x * NTOK] = 1.f;
        } else if (bx < 10) {
            const int i4 = (bx - 1) * 256 + threadIdx.x;   // < 2304
            *(float4*)(cmax + (size_t)i4 * 4) = (float4){0.f, 0.f, 0.f, 0.f};
        }
        return;
    }
    const size_t idx = ((size_t)blockIdx.x * TPB + threadIdx.x) * 8;
    union { unsigned int u[4]; short8 s; } pk;
    if (z <= 1) {
        if (idx >= APLANE) return;
        const int row = (int)(idx / DIM);
        const int M = z ? MROWS : ROWS;
        const float* src = z ? mask : x;
        if (row < M) {
            float a[8];
            *(float4*)&a[0] = *(const float4*)(src + idx);
            *(float4*)&a[4] = *(const float4*)(src + idx + 4);
            pk.u[0] = cvtpk(a[0], a[1]); pk.u[1] = cvtpk(a[2], a[3]);
            pk.u[2] = cvtpk(a[4], a[5]); pk.u[3] = cvtpk(a[6], a[7]);
            if (z == 1) {
                // mask values are 0/1 -> sum>0 == any nonzero == (mean>0)
                const float s = ((a[0] + a[1]) + (a[2] + a[3])) + ((a[4] + a[5]) + (a[6] + a[7]));
                if (s > 0.f) {
                    const int b = row >> 10, j = row & 1023;
                    upd[b * NTOK + j + 1] = 1.f;
                }
            }
        } else {
            pk.u[0] = pk.u[1] = pk.u[2] = pk.u[3] = 0u;
        }
        *(short8*)(Abf + (size_t)z * APLANE + idx) = pk.s;
    } else {
        const size_t tot = (z == 2) ? (size_t)QK3 * DIM : (size_t)DIM * DIM;
        if (idx >= tot) return;
        const float* src = (z == 2) ? wqkv : wout;
        unsigned short* dst = (z == 2) ? Wq : Wo;
        float a[8];
        *(float4*)&a[0] = *(const float4*)(src + idx);
        *(float4*)&a[4] = *(const float4*)(src + idx + 4);
        union { unsigned int u[4]; short8 s; } pa;
        pk.u[0] = cvtpk(a[0], a[1]); pk.u[1] = cvtpk(a[2], a[3]);
        pk.u[2] = cvtpk(a[4], a[5]); pk.u[3] = cvtpk(a[6], a[7]);
#pragma unroll
        for (int i = 0; i < 4; ++i) pa.u[i] = pk.u[i] & 0x7FFF7FFFu;
        *(short8*)(dst + idx) = pk.s;
        *(short8*)(dst + tot + idx) = pa.s;
    }
}

// ---------------------------------------------------------------------------
// K1: bf16 MFMA GEMM (R12): 8-wave blocks + BK=32 dbuf -> 32 KB LDS ->
// 4 blocks/CU x 8 waves = 32 waves/CU = 8 waves/SIMD (full occupancy at
// VGPR 52). R11 validated the TLP mechanism (4 waves/SIMD: 54.4->48.5us);
// this doubles it again. Total LDS/stage traffic unchanged (per-phase
// traffic halves as phases double) — unlike R4/R5 which changed tile
// economics. R4's 24-phase failure was at 2 waves/SIMD with no barrier
// cover; 4 independent block-barrier-domains/CU now cover each other.
// Swizzle uses (row>>1)&3 (row&3 would correlate chunk with row parity ->
// 4-way conflict; >>1 spreads a quad's 16 lanes over 8 slots = 2-way = free).
// Staging: 1 gl_lds per matrix per thread -> vmcnt(2).
// ---------------------------------------------------------------------------
__global__ __launch_bounds__(512)
void k_gemm_qkv_mfma(const unsigned short* __restrict__ Abf,
                     const unsigned short* __restrict__ Wq,
                     unsigned short* __restrict__ qkv16,
                     unsigned short* __restrict__ qkvm16,
                     float* __restrict__ cmax)
{
    const int bid = blockIdx.x;
    const int xcd = bid & 7, rr = bid >> 3;
    const int id = (xcd < 4) ? (xcd * 149 + rr) : (596 + (xcd - 4) * 148 + rr);
    const int z = id / 594;
    const int rem = id - z * 594;
    const int by = rem / 18, bx = rem - by * 18;
    const int rowT = by * 128, colT = bx * 128;
    if (z == 1 && rowT >= MROWS) return;
    const unsigned short* A = Abf + (size_t)z * APLANE;
    const unsigned short* B = Wq + (size_t)z * QK3 * DIM;

    __shared__ unsigned short As[2][128 * 32];   // 2 x 8 KB
    __shared__ unsigned short Bs[2][128 * 32];   // 2 x 8 KB  (32 KB total)

    const int t = threadIdx.x;                   // 0..511
    const int w = t >> 6, lane = t & 63, l15 = lane & 15, quad = lane >> 4;
    const int wm = (w & 3) * 32, wn = (w >> 2) * 64;

    // staging: row = t>>2, ch = t&3 (4 chunks of 8 u16 per row); source col
    // pre-inverse-swizzled with (row>>1)&3, LDS dest linear (rule #21).
    auto stage = [&](int buf, int k0) {
        const int row = t >> 2, ch = t & 3;
        const int gc = k0 + ((ch ^ ((row >> 1) & 3)) << 3);
        gl_lds16(A + (size_t)(rowT + row) * DIM + gc, As[buf] + (size_t)t * 8);
        gl_lds16(B + (size_t)(colT + row) * DIM + gc, Bs[buf] + (size_t)t * 8);
    };

    f32x4 acc[2][4];
#pragma unroll
    for (int i = 0; i < 2; ++i)
#pragma unroll
        for (int j = 0; j < 4; ++j) acc[i][j] = (f32x4){0.f, 0.f, 0.f, 0.f};

    stage(0, 0);
#pragma clang loop unroll(disable)
    for (int kt = 0; kt < 24; ++kt) {
        const int cur = kt & 1;
        if (kt < 23) {
            stage(cur ^ 1, (kt + 1) * 32);                       // 2 loads in flight
            asm volatile("s_waitcnt vmcnt(2)" ::: "memory");     // cur tile's 2 done
        } else {
            asm volatile("s_waitcnt vmcnt(0)" ::: "memory");
        }
        __builtin_amdgcn_s_barrier();
        __builtin_amdgcn_sched_barrier(0);
        const unsigned short* as = As[cur];
        const unsigned short* bs = Bs[cur];
        const int rc = (quad ^ ((l15 >> 1) & 3)) << 3;
        short8 fa[2], fb[4];
#pragma unroll
        for (int mi = 0; mi < 2; ++mi)
            fa[mi] = *(const short8*)(as + (wm + mi * 16 + l15) * 32 + rc);
#pragma unroll
        for (int ni = 0; ni < 4; ++ni)
            fb[ni] = *(const short8*)(bs + (wn + ni * 16 + l15) * 32 + rc);
        __builtin_amdgcn_s_setprio(1);
#pragma unroll
        for (int mi = 0; mi < 2; ++mi)
#pragma unroll
            for (int ni = 0; ni < 4; ++ni)
                acc[mi][ni] = __builtin_amdgcn_mfma_f32_16x16x32_bf16(fa[mi], fb[ni], acc[mi][ni], 0, 0, 0);
        __builtin_amdgcn_s_setprio(0);
        asm volatile("s_waitcnt lgkmcnt(0)" ::: "memory");       // all ds_reads landed
        __builtin_amdgcn_s_barrier();                            // before buf reuse
    }

    float cm[4] = {0.f, 0.f, 0.f, 0.f};
#pragma unroll
    for (int mi = 0; mi < 2; ++mi)
#pragma unroll
        for (int ni = 0; ni < 4; ++ni) {
            const int col = colT + wn + ni * 16 + l15;
#pragma unroll
            for (int r = 0; r < 4; ++r) {
                const int row = rowT + wm + mi * 16 + quad * 4 + r;
                const float v = acc[mi][ni][r];
                if (z == 0) {
                    if (row < ROWS) qkv16[(size_t)row * QK3 + col] = f2bf(v);
                } else {
                    qkvm16[(size_t)row * QK3 + col] = f2bf(v);
                    cm[ni] = fmaxf(cm[ni], v);
                }
            }
        }
    if (z == 1) {
        const int bb = rowT >> 10;
#pragma unroll
        for (int ni = 0; ni < 4; ++ni) {
            float m = cm[ni];
            m = fmaxf(m, __shfl_xor(m, 16, 64));
            m = fmaxf(m, __shfl_xor(m, 32, 64));
            if (quad == 0)
                atomicMax((int*)&cmax[bb * QK3 + colT + wn + ni * 16 + l15], __float_as_int(m));
        }
    }
}

// ---------------------------------------------------------------------------
// K3: prep in FRAGMENT-MAJOR layout (cvtpk version, unchanged)
// ---------------------------------------------------------------------------
__global__ __launch_bounds__(TPB)
void k_prep(const unsigned short* __restrict__ qkv16,
            const unsigned short* __restrict__ qkvm16,
            const float* __restrict__ cmax, unsigned short* __restrict__ qe,
            unsigned short* __restrict__ kfrag, unsigned short* __restrict__ vfrag)
{
    __shared__ unsigned short Vt_l[128 * 66];
    const int t = threadIdx.x;
    const int nt = blockIdx.x, h = blockIdx.y, b = blockIdx.z;
    const int bh = b * HEADS + h;
    const int nl = t >> 2, ds0 = (t & 3) * 16;
    const int n = nt * 64 + nl;
    const bool valid = n < NTOK;
    const int col0 = h * 64 + ds0;

    unsigned short q16[16] __attribute__((aligned(16))) = {0};
    unsigned short k16[16] __attribute__((aligned(16))) = {0};
    unsigned short v16[16] __attribute__((aligned(16))) = {0};
    unsigned short qm16[16] __attribute__((aligned(16)));
    unsigned short km16[16] __attribute__((aligned(16)));
    unsigned short vm16[16] __attribute__((aligned(16)));
    float cq[16], ck[16], cv[16];

    const bool useM = valid && (n > 0);
    if (valid) {
        const size_t br = (size_t)(b * NTOK + n) * QK3 + col0;
        *(short8*)&q16[0] = *(const short8*)(qkv16 + br);
        *(short8*)&q16[8] = *(const short8*)(qkv16 + br + 8);
        *(short8*)&k16[0] = *(const short8*)(qkv16 + br + 768);
        *(short8*)&k16[8] = *(const short8*)(qkv16 + br + 776);
        *(short8*)&v16[0] = *(const short8*)(qkv16 + br + 1536);
        *(short8*)&v16[8] = *(const short8*)(qkv16 + br + 1544);
    }
    if (useM) {
        const size_t mr = (size_t)(b * 1024 + (n - 1)) * QK3 + col0;
        *(short8*)&qm16[0] = *(const short8*)(qkvm16 + mr);
        *(short8*)&qm16[8] = *(const short8*)(qkvm16 + mr + 8);
        *(short8*)&km16[0] = *(const short8*)(qkvm16 + mr + 768);
        *(short8*)&km16[8] = *(const short8*)(qkvm16 + mr + 776);
        *(short8*)&vm16[0] = *(const short8*)(qkvm16 + mr + 1536);
        *(short8*)&vm16[8] = *(const short8*)(qkvm16 + mr + 1544);
        const int cb = b * QK3 + col0;
#pragma unroll
        for (int i = 0; i < 4; ++i) {
            *(float4*)&cq[i * 4] = *(const float4*)(cmax + cb + i * 4);
            *(float4*)&ck[i * 4] = *(const float4*)(cmax + cb + 768 + i * 4);
            *(float4*)&cv[i * 4] = *(const float4*)(cmax + cb + 1536 + i * 4);
        }
    }

    float fq[16], fk[16];
#pragma unroll
    for (int idx = 0; idx < 16; ++idx) {
        const float qm = useM ? bf2f(qm16[idx]) / (1e-6f + cq[idx]) : 1.f;
        const float km = useM ? bf2f(km16[idx]) / (1e-6f + ck[idx]) : 1.f;
        const float vm = valid ? (useM ? bf2f(vm16[idx]) / (1e-6f + cv[idx]) : 1.f) : 0.f;
        // 0.125 * log2(e): softmax becomes exp2(S' - 10*log2(e))
        fq[idx] = bf2f(q16[idx]) * qm * 0.18033688f;
        fk[idx] = bf2f(k16[idx]) * km;
        const int d = ds0 + idx;
        Vt_l[d * 66 + nl]        = f2bf(bf2f(v16[idx]) * vm);
        Vt_l[(64 + d) * 66 + nl] = f2bf(vm);
    }
    union { unsigned int u[4]; short8 s; } pq0, pq1, pk0, pk1;
#pragma unroll
    for (int i = 0; i < 4; ++i) {
        pq0.u[i] = cvtpk(fq[2 * i],     fq[2 * i + 1]);
        pq1.u[i] = cvtpk(fq[8 + 2 * i], fq[9 + 2 * i]);
        pk0.u[i] = cvtpk(fk[2 * i],     fk[2 * i + 1]);
        pk1.u[i] = cvtpk(fk[8 + 2 * i], fk[9 + 2 * i]);
    }
    // Q: row-major, unconditional (zeros for invalid rows)
    {
        unsigned short* qp = qe + ((size_t)bh * NPAD + n) * 64 + ds0;
        *(short8*)qp       = pq0.s;
        *(short8*)(qp + 8) = pq1.s;
    }
    // K: fragment-major, unconditional
    {
        const int nc = nl >> 4, l15 = nl & 15;
        const int kk = ds0 >> 5, qb = (ds0 & 31) >> 3;   // quads qb, qb+1
        unsigned short* kp = kfrag + (((size_t)bh * 17 + nt) * 8 + kk * 4 + nc) * 512;
        *(short8*)(kp + ((size_t)(qb * 16 + l15)) * 8)       = pk0.s;
        *(short8*)(kp + ((size_t)((qb + 1) * 16 + l15)) * 8) = pk1.s;
    }
    __syncthreads();
    // V^T: fragment-major from the LDS transpose
    const int c = t >> 1, nh = (t & 1) * 32;
    unsigned short ov[32] __attribute__((aligned(16)));
#pragma unroll
    for (int i = 0; i < 32; ++i) ov[i] = Vt_l[c * 66 + nh + i];
    const int c8 = c >> 4, l15v = c & 15, kkv = nh >> 5;
    unsigned short* vp = vfrag + (((size_t)bh * 17 + nt) * 16 + c8 * 2 + kkv) * 512 + (size_t)l15v * 8;
#pragma unroll
    for (int qd = 0; qd < 4; ++qd)
        *(short8*)(vp + (size_t)qd * 128) = *(short8*)(ov + qd * 8);
}

// ---------------------------------------------------------------------------
// K4: MFMA flash attention — 2-q-tile/wave version (grid 33x48 = 1584).
// R9 proved the 2-tile load-amortization IS the optimization. Do not churn.
// ---------------------------------------------------------------------------
__global__ __launch_bounds__(64, 2)
void k_attn(const unsigned short* __restrict__ qe, const unsigned short* __restrict__ kfrag,
            const unsigned short* __restrict__ vfrag, const float* __restrict__ upd,
            unsigned short* __restrict__ ab2)
{
    const int flat = blockIdx.y * 33 + blockIdx.x;
    const int d2 = (flat & 7) * 198 + (flat >> 3);   // 1584 = 8*198, bijective
    const int bh = d2 / 33, qt = d2 - bh * 33;
    const int b = bh / HEADS, h = bh - b * HEADS;
    const int lane = threadIdx.x;
    const int l15 = lane & 15, quad = lane >> 4;
    const int q0 = qt * 32;

    short8 qf[2][2];
#pragma unroll
    for (int j = 0; j < 2; ++j) {
        const unsigned short* qp = qe + ((size_t)bh * NPAD + q0 + j * 16 + l15) * 64 + (quad << 3);
        qf[j][0] = *(const short8*)qp;
        qf[j][1] = *(const short8*)(qp + 32);
    }
    const int pA = (quad & 1) * 32 + l15;
    const int pB = pA + 16;
    const bool lo32 = (lane < 32);

    const unsigned short* kb = kfrag + (size_t)bh * (17 * 8 * 512) + (size_t)lane * 8;
    const unsigned short* vb = vfrag + (size_t)bh * (17 * 16 * 512) + (size_t)lane * 8;

    short8 kf[8], vf[16];
#pragma unroll
    for (int g = 0; g < 8; ++g) kf[g] = *(const short8*)(kb + g * 512);
#pragma unroll
    for (int g = 0; g < 16; ++g) vf[g] = *(const short8*)(vb + g * 512);

    f32x4 acc[2][8];
    float lac[2] = {0.f, 0.f};
#pragma unroll
    for (int j = 0; j < 2; ++j)
#pragma unroll
        for (int g = 0; g < 8; ++g) acc[j][g] = (f32x4){0.f, 0.f, 0.f, 0.f};

    const float EC = 14.4269504f;   // 10*log2(e)

#pragma clang loop unroll(disable)
    for (int kt = 0; kt < 17; ++kt) {
        // S^T (q pre-scaled by 0.125*log2e)
        f32x4 s[2][4];
        __builtin_amdgcn_s_setprio(1);
#pragma unroll
        for (int nc = 0; nc < 4; ++nc) {
#pragma unroll
            for (int j = 0; j < 2; ++j) {
                f32x4 z = (f32x4){0.f, 0.f, 0.f, 0.f};
                z = __builtin_amdgcn_mfma_f32_16x16x32_bf16(kf[nc], qf[j][0], z, 0, 0, 0);
                z = __builtin_amdgcn_mfma_f32_16x16x32_bf16(kf[4 + nc], qf[j][1], z, 0, 0, 0);
                s[j][nc] = z;
            }
        }
        __builtin_amdgcn_s_setprio(0);
        // prefetch next K tile
        if (kt < 16) {
            const unsigned short* kn = kb + (size_t)(kt + 1) * 4096;
#pragma unroll
            for (int g = 0; g < 8; ++g) kf[g] = *(const short8*)(kn + g * 512);
        }
        // p = exp2(S' - EC); pack via v_cvt_pk_bf16_f32; accumulate l in-register
        short8 pf[2][2];
#pragma unroll
        for (int j = 0; j < 2; ++j) {
            unsigned int dA[4], dB[4];
            float psum = 0.f, p00 = 0.f;
#pragma unroll
            for (int nc = 0; nc < 4; ++nc) {
                const float p0 = __builtin_amdgcn_exp2f(s[j][nc][0] - EC);
                const float p1 = __builtin_amdgcn_exp2f(s[j][nc][1] - EC);
                const float p2 = __builtin_amdgcn_exp2f(s[j][nc][2] - EC);
                const float p3 = __builtin_amdgcn_exp2f(s[j][nc][3] - EC);
                dA[nc] = cvtpk(p0, p1);
                dB[nc] = cvtpk(p2, p3);
                psum += (p0 + p1) + (p2 + p3);
                if (nc == 0) p00 = p0;
            }
            if (kt < 16) lac[j] += psum;          // all 64 rows valid
            else if (quad == 0) lac[j] += p00;    // only n==1024 valid in last tile
            union { int i[4]; short8 s; } u0, u1;
            {
                const int a0 = __shfl((int)dA[0], pA, 64), a1 = __shfl((int)dA[1], pA, 64);
                const int b0 = __shfl((int)dB[0], pA, 64), b1 = __shfl((int)dB[1], pA, 64);
                const int a2 = __shfl((int)dA[0], pB, 64), a3 = __shfl((int)dA[1], pB, 64);
                const int b2 = __shfl((int)dB[0], pB, 64), b3 = __shfl((int)dB[1], pB, 64);
                u0.i[0] = lo32 ? a0 : a1;
                u0.i[1] = lo32 ? b0 : b1;
                u0.i[2] = lo32 ? a2 : a3;
                u0.i[3] = lo32 ? b2 : b3;
            }
            {
                const int a0 = __shfl((int)dA[2], pA, 64), a1 = __shfl((int)dA[3], pA, 64);
                const int b0 = __shfl((int)dB[2], pA, 64), b1 = __shfl((int)dB[3], pA, 64);
                const int a2 = __shfl((int)dA[2], pB, 64), a3 = __shfl((int)dA[3], pB, 64);
                const int b2 = __shfl((int)dB[2], pB, 64), b3 = __shfl((int)dB[3], pB, 64);
                u1.i[0] = lo32 ? a0 : a1;
                u1.i[1] = lo32 ? b0 : b1;
                u1.i[2] = lo32 ? a2 : a3;
                u1.i[3] = lo32 ? b2 : b3;
            }
            pf[j][0] = u0.s;
            pf[j][1] = u1.s;
        }
        // O^T += V^T P^T
        __builtin_amdgcn_s_setprio(1);
#pragma unroll
        for (int g = 0; g < 8; ++g) {
#pragma unroll
            for (int j = 0; j < 2; ++j) {
                acc[j][g] = __builtin_amdgcn_mfma_f32_16x16x32_bf16(vf[2 * g],     pf[j][0], acc[j][g], 0, 0, 0);
                acc[j][g] = __builtin_amdgcn_mfma_f32_16x16x32_bf16(vf[2 * g + 1], pf[j][1], acc[j][g], 0, 0, 0);
            }
        }
        __builtin_amdgcn_s_setprio(0);
        // prefetch next V tile
        if (kt < 16) {
            const unsigned short* vn = vb + (size_t)(kt + 1) * 8192;
#pragma unroll
            for (int g = 0; g < 16; ++g) vf[g] = *(const short8*)(vn + g * 512);
        }
    }

#pragma unroll
    for (int j = 0; j < 2; ++j) {
        float lq = lac[j];
        lq += __shfl_xor(lq, 16, 64);
        lq += __shfl_xor(lq, 32, 64);   // every lane now holds l for q = l15
        const int qrow = q0 + j * 16 + l15;
        if (qrow < NTOK) {
            const size_t rg = (size_t)b * NTOK + qrow;
            const float inv = upd[rg] / lq;
#pragma unroll
            for (int g = 0; g < 8; ++g) {
                uint2 pk;
                pk.x = cvtpk(acc[j][g][0] * inv, acc[j][g][1] * inv);
                pk.y = cvtpk(acc[j][g][2] * inv, acc[j][g][3] * inv);
                const size_t addr = (size_t)(g >> 2) * APLANE + rg * DIM + h * 64 + (g & 3) * 16 + quad * 4;
                *(uint2*)(ab2 + addr) = pk;
            }
        }
    }
}

// ---------------------------------------------------------------------------
// K5: bf16 MFMA out-GEMMs — R11 8-wave BK=64 version (kept unchanged;
// single-variable discipline: only K1 changes this round).
// ---------------------------------------------------------------------------
__global__ __launch_bounds__(512)
void k_gemm_out_mfma(const unsigned short* __restrict__ ab2,
                     const unsigned short* __restrict__ Wo,
                     const float* __restrict__ bout, float* __restrict__ dout)
{
    const int bid = blockIdx.x;
    const int xcd = bid & 7, rr = bid >> 3;
    const int id = (xcd < 4) ? (xcd * 50 + rr) : (200 + (xcd - 4) * 49 + rr);
    const int z = id / 198;
    const int rem = id - z * 198;
    const int by = rem / 6, bx = rem - by * 6;
    const int rowT = by * 128, colT = bx * 128;

    const unsigned short* A = ab2 + (size_t)z * APLANE;
    const unsigned short* B = Wo + (size_t)z * DIM * DIM;

    __shared__ unsigned short As[2][128 * 64];
    __shared__ unsigned short Bs[2][128 * 64];

    const int t = threadIdx.x;                   // 0..511
    const int w = t >> 6, lane = t & 63, l15 = lane & 15, quad = lane >> 4;
    const int wm = (w & 3) * 32, wn = (w >> 2) * 64;

    auto stage = [&](int buf, int k0) {
#pragma unroll
        for (int p = 0; p < 2; ++p) {
            const int i = p * 512 + t;
            const int row = i >> 3, ch = i & 7;
            const int gc = k0 + ((ch ^ (row & 7)) << 3);
            gl_lds16(A + (size_t)(rowT + row) * DIM + gc, As[buf] + (size_t)i * 8);
            gl_lds16(B + (size_t)(colT + row) * DIM + gc, Bs[buf] + (size_t)i * 8);
        }
    };

    f32x4 acc[2][4];
#pragma unroll
    for (int i = 0; i < 2; ++i)
#pragma unroll
        for (int j = 0; j < 4; ++j) acc[i][j] = (f32x4){0.f, 0.f, 0.f, 0.f};

    stage(0, 0);
#pragma clang loop unroll(disable)
    for (int kt = 0; kt < 12; ++kt) {
        const int cur = kt & 1;
        if (kt < 11) {
            stage(cur ^ 1, (kt + 1) * 64);
            asm volatile("s_waitcnt vmcnt(4)" ::: "memory");
        } else {
            asm volatile("s_waitcnt vmcnt(0)" ::: "memory");
        }
        __builtin_amdgcn_s_barrier();
        __builtin_amdgcn_sched_barrier(0);
        const unsigned short* as = As[cur];
        const unsigned short* bs = Bs[cur];
        short8 fa[2][2], fb[2][4];
#pragma unroll
        for (int kk = 0; kk < 2; ++kk) {
            const int rc = ((kk * 4 + quad) ^ (l15 & 7)) << 3;
#pragma unroll
            for (int mi = 0; mi < 2; ++mi)
                fa[kk][mi] = *(const short8*)(as + (wm + mi * 16 + l15) * 64 + rc);
#pragma unroll
            for (int ni = 0; ni < 4; ++ni)
                fb[kk][ni] = *(const short8*)(bs + (wn + ni * 16 + l15) * 64 + rc);
        }
        __builtin_amdgcn_s_setprio(1);
#pragma unroll
        for (int kk = 0; kk < 2; ++kk)
#pragma unroll
            for (int mi = 0; mi < 2; ++mi)
#pragma unroll
                for (int ni = 0; ni < 4; ++ni)
                    acc[mi][ni] = __builtin_amdgcn_mfma_f32_16x16x32_bf16(fa[kk][mi], fb[kk][ni], acc[mi][ni], 0, 0, 0);
        __builtin_amdgcn_s_setprio(0);
        asm volatile("s_waitcnt lgkmcnt(0)" ::: "memory");
        __builtin_amdgcn_s_barrier();
    }

#pragma unroll
    for (int mi = 0; mi < 2; ++mi)
#pragma unroll
        for (int ni = 0; ni < 4; ++ni) {
            const int col = colT + wn + ni * 16 + l15;
            const float bb = (z == 0) ? bout[col] : 0.f;
#pragma unroll
            for (int r = 0; r < 4; ++r) {
                const int row = rowT + wm + mi * 16 + quad * 4 + r;
                if (row >= ROWS) continue;
                const int b = row / NTOK, n = row % NTOK;
                if (z == 0) {
                    dout[(size_t)row * DIM + col] = acc[mi][ni][r] + bb;
                } else if (n >= 1) {
                    dout[OUT0 + ((size_t)(b * (NTOK - 1) + (n - 1))) * DIM + col] = acc[mi][ni][r];
                }
            }
        }
}

extern "C" void kernel_launch(void* const* d_in, const int* in_sizes, int n_in,
                              void* d_out, int out_size, void* d_ws, size_t ws_size,
                              hipStream_t stream)
{
    const float* x    = (const float*)d_in[0];
    const float* mask = (const float*)d_in[1];
    const float* wqkv = (const float*)d_in[2];
    const float* wout = (const float*)d_in[3];
    const float* bout = (const float*)d_in[4];
    float* ws = (float*)d_ws;
    unsigned short* qkv16  = (unsigned short*)(ws + OFF_QKV16);
    unsigned short* qkvm16 = (unsigned short*)(ws + OFF_QKVM16);
    unsigned short* qe  = (unsigned short*)(ws + OFF_QE);
    unsigned short* kfr = (unsigned short*)(ws + OFF_KF);
    unsigned short* vfr = (unsigned short*)(ws + OFF_VF);
    unsigned short* abf = (unsigned short*)(ws + OFF_ABF);
    unsigned short* wq  = (unsigned short*)(ws + OFF_WQ);
    unsigned short* wo  = (unsigned short*)(ws + OFF_WO);
    float* cmax = ws + OFF_CMAX;
    float* upd  = ws + OFF_UPD;
    float* out  = (float*)d_out;

    hipMemsetAsync(upd, 0, ROWS * sizeof(float), stream);
    hipLaunchKernelGGL(k_cvt,           dim3(1584, 1, 5), dim3(TPB), 0, stream, x, mask, wqkv, wout, abf, wq, wo, upd, cmax);
    hipLaunchKernelGGL(k_gemm_qkv_mfma, dim3(1188),       dim3(512), 0, stream, abf, wq, qkv16, qkvm16, cmax);
    hipLaunchKernelGGL(k_prep,          dim3(17, 12, 4),  dim3(TPB), 0, stream, qkv16, qkvm16, cmax, qe, kfr, vfr);
    hipLaunchKernelGGL(k_attn,          dim3(33, 48),     dim3(64),  0, stream, qe, kfr, vfr, upd, abf);
    hipLaunchKernelGGL(k_gemm_out_mfma, dim3(396),        dim3(512), 0, stream, abf, wo, bout, out);
}

// Round 13
// 200.498 us; speedup vs baseline: 1.0155x; 1.0155x over previous
//
#include <hip/hip_runtime.h>
#include <cmath>

#define TPB 256

static const int NTOK  = 1025;
static const int DIM   = 768;
static const int HEADS = 12;
static const int QK3   = 2304;
static const int ROWS  = 4 * NTOK;        // 4100
static const int MROWS = 4 * (NTOK - 1);  // 4096
static const int MPAD  = 4224;            // 33*128 padded A rows
static const int NPAD  = 1088;            // 17*64
static const size_t OUT0 = (size_t)ROWS * DIM;
static const size_t APLANE = (size_t)MPAD * DIM;   // bf16 per plane

// workspace offsets in floats (qkv/qkvm bf16)
static const size_t OFF_QKV16  = 0;          // 4100*2304 u16 = 4,723,200 f
static const size_t OFF_QKVM16 = 4800000;    // 4096*2304 u16 = 4,718,592 f
static const size_t OFF_QE     = 9600000;    // 48*1088*64 u16 = 1,671,168 f
static const size_t OFF_KF     = 11300000;   // 48*17*8*512 u16 = 1,671,168 f (frag-major K)
static const size_t OFF_VF     = 13000000;   // 48*17*16*512 u16 = 3,342,336 f (frag-major V^T)
static const size_t OFF_ABF    = 16400000;   // 2*4224*768 u16 = 3,244,032 f
static const size_t OFF_WQ     = 19700000;   // 2*2304*768 u16 = 1,769,472 f
static const size_t OFF_WO     = 21500000;   // 2*768*768 u16  =   589,824 f
static const size_t OFF_CMAX   = 22100000;   // 9,216 f
static const size_t OFF_UPD    = 22110000;   // 4,100 f

typedef __attribute__((ext_vector_type(8))) short short8;
typedef __attribute__((ext_vector_type(4))) float f32x4;

__device__ __forceinline__ unsigned short f2bf(float f) {
    union { float f; unsigned int u; } c; c.f = f;
    unsigned int u = c.u + 0x7fffu + ((c.u >> 16) & 1u);  // RNE
    return (unsigned short)(u >> 16);
}
__device__ __forceinline__ float bf2f(unsigned short u) {
    union { unsigned int u; float f; } c; c.u = (unsigned int)u << 16;
    return c.f;
}
// packed f32x2 -> bf16x2 in ONE instruction (RNE)
__device__ __forceinline__ unsigned int cvtpk(float a, float b) {
    unsigned int r;
    asm("v_cvt_pk_bf16_f32 %0, %1, %2" : "=v"(r) : "v"(a), "v"(b));
    return r;
}
__device__ __forceinline__ void gl_lds16(const unsigned short* g, unsigned short* l) {
    __builtin_amdgcn_global_load_lds(
        (const __attribute__((address_space(1))) unsigned int*)g,
        (__attribute__((address_space(3))) unsigned int*)l, 16, 0, 0);
}

// ---------------------------------------------------------------------------
// K0: fp32 -> bf16 conversions (cvtpk version).
// upd flags fused into z=1; z=4: bx==0 CLS upd rows, bx 1..9 cmax zero.
// ---------------------------------------------------------------------------
__global__ __launch_bounds__(TPB)
void k_cvt(const float* __restrict__ x, const float* __restrict__ mask,
           const float* __restrict__ wqkv, const float* __restrict__ wout,
           unsigned short* __restrict__ Abf, unsigned short* __restrict__ Wq,
           unsigned short* __restrict__ Wo, float* __restrict__ upd,
           float* __restrict__ cmax)
{
    const int z = blockIdx.z;
    if (z == 4) {
        const int bx = blockIdx.x;
        if (bx == 0) {
            if (threadIdx.x < 4) upd[threadIdx.x * NTOK] = 1.f;
        } else if (bx < 10) {
            const int i4 = (bx - 1) * 256 + threadIdx.x;   // < 2304
            *(float4*)(cmax + (size_t)i4 * 4) = (float4){0.f, 0.f, 0.f, 0.f};
        }
        return;
    }
    const size_t idx = ((size_t)blockIdx.x * TPB + threadIdx.x) * 8;
    union { unsigned int u[4]; short8 s; } pk;
    if (z <= 1) {
        if (idx >= APLANE) return;
        const int row = (int)(idx / DIM);
        const int M = z ? MROWS : ROWS;
        const float* src = z ? mask : x;
        if (row < M) {
            float a[8];
            *(float4*)&a[0] = *(const float4*)(src + idx);
            *(float4*)&a[4] = *(const float4*)(src + idx + 4);
            pk.u[0] = cvtpk(a[0], a[1]); pk.u[1] = cvtpk(a[2], a[3]);
            pk.u[2] = cvtpk(a[4], a[5]); pk.u[3] = cvtpk(a[6], a[7]);
            if (z == 1) {
                // mask values are 0/1 -> sum>0 == any nonzero == (mean>0)
                const float s = ((a[0] + a[1]) + (a[2] + a[3])) + ((a[4] + a[5]) + (a[6] + a[7]));
                if (s > 0.f) {
                    const int b = row >> 10, j = row & 1023;
                    upd[b * NTOK + j + 1] = 1.f;
                }
            }
        } else {
            pk.u[0] = pk.u[1] = pk.u[2] = pk.u[3] = 0u;
        }
        *(short8*)(Abf + (size_t)z * APLANE + idx) = pk.s;
    } else {
        const size_t tot = (z == 2) ? (size_t)QK3 * DIM : (size_t)DIM * DIM;
        if (idx >= tot) return;
        const float* src = (z == 2) ? wqkv : wout;
        unsigned short* dst = (z == 2) ? Wq : Wo;
        float a[8];
        *(float4*)&a[0] = *(const float4*)(src + idx);
        *(float4*)&a[4] = *(const float4*)(src + idx + 4);
        union { unsigned int u[4]; short8 s; } pa;
        pk.u[0] = cvtpk(a[0], a[1]); pk.u[1] = cvtpk(a[2], a[3]);
        pk.u[2] = cvtpk(a[4], a[5]); pk.u[3] = cvtpk(a[6], a[7]);
#pragma unroll
        for (int i = 0; i < 4; ++i) pa.u[i] = pk.u[i] & 0x7FFF7FFFu;
        *(short8*)(dst + idx) = pk.s;
        *(short8*)(dst + tot + idx) = pa.s;
    }
}

// ---------------------------------------------------------------------------
// K1: bf16 MFMA GEMM — R11 best point (48.5us, harness-verified in the
// 201.0us total): 128x128x64 tile, 8 waves (4M x 2N, per-wave 32x64),
// BK=64 dbuf (64 KB -> 2 blk/CU = 4 waves/SIMD), counted vmcnt(4),
// 2 barriers/phase, chunk-XOR swizzle, XCD-chunk block swizzle.
// R12 scan endpoint: BK=32 @ 8 waves/SIMD raised occupancy 29->47% but
// cost +1.7us (phase-count overhead > extra TLP). This is the measured
// optimum of {schedule family x tile x waves/SIMD}. Do not churn.
// ---------------------------------------------------------------------------
__global__ __launch_bounds__(512)
void k_gemm_qkv_mfma(const unsigned short* __restrict__ Abf,
                     const unsigned short* __restrict__ Wq,
                     unsigned short* __restrict__ qkv16,
                     unsigned short* __restrict__ qkvm16,
                     float* __restrict__ cmax)
{
    const int bid = blockIdx.x;
    const int xcd = bid & 7, rr = bid >> 3;
    const int id = (xcd < 4) ? (xcd * 149 + rr) : (596 + (xcd - 4) * 148 + rr);
    const int z = id / 594;
    const int rem = id - z * 594;
    const int by = rem / 18, bx = rem - by * 18;
    const int rowT = by * 128, colT = bx * 128;
    if (z == 1 && rowT >= MROWS) return;
    const unsigned short* A = Abf + (size_t)z * APLANE;
    const unsigned short* B = Wq + (size_t)z * QK3 * DIM;

    __shared__ unsigned short As[2][128 * 64];   // 2 x 16 KB
    __shared__ unsigned short Bs[2][128 * 64];   // 2 x 16 KB  (64 KB total)

    const int t = threadIdx.x;                   // 0..511
    const int w = t >> 6, lane = t & 63, l15 = lane & 15, quad = lane >> 4;
    const int wm = (w & 3) * 32, wn = (w >> 2) * 64;

    // staging: i = p*512+t (p<2): row = i>>3, ch = i&7; source col
    // pre-inverse-swizzled, LDS dest linear (rule #21). 4 gl_lds/thread.
    auto stage = [&](int buf, int k0) {
#pragma unroll
        for (int p = 0; p < 2; ++p) {
            const int i = p * 512 + t;
            const int row = i >> 3, ch = i & 7;
            const int gc = k0 + ((ch ^ (row & 7)) << 3);
            gl_lds16(A + (size_t)(rowT + row) * DIM + gc, As[buf] + (size_t)i * 8);
            gl_lds16(B + (size_t)(colT + row) * DIM + gc, Bs[buf] + (size_t)i * 8);
        }
    };

    f32x4 acc[2][4];
#pragma unroll
    for (int i = 0; i < 2; ++i)
#pragma unroll
        for (int j = 0; j < 4; ++j) acc[i][j] = (f32x4){0.f, 0.f, 0.f, 0.f};

    stage(0, 0);
#pragma clang loop unroll(disable)
    for (int kt = 0; kt < 12; ++kt) {
        const int cur = kt & 1;
        if (kt < 11) {
            stage(cur ^ 1, (kt + 1) * 64);                       // 4 loads in flight
            asm volatile("s_waitcnt vmcnt(4)" ::: "memory");     // cur tile's 4 done
        } else {
            asm volatile("s_waitcnt vmcnt(0)" ::: "memory");
        }
        __builtin_amdgcn_s_barrier();
        __builtin_amdgcn_sched_barrier(0);
        const unsigned short* as = As[cur];
        const unsigned short* bs = Bs[cur];
        short8 fa[2][2], fb[2][4];
#pragma unroll
        for (int kk = 0; kk < 2; ++kk) {
            const int rc = ((kk * 4 + quad) ^ (l15 & 7)) << 3;
#pragma unroll
            for (int mi = 0; mi < 2; ++mi)
                fa[kk][mi] = *(const short8*)(as + (wm + mi * 16 + l15) * 64 + rc);
#pragma unroll
            for (int ni = 0; ni < 4; ++ni)
                fb[kk][ni] = *(const short8*)(bs + (wn + ni * 16 + l15) * 64 + rc);
        }
        __builtin_amdgcn_s_setprio(1);
#pragma unroll
        for (int kk = 0; kk < 2; ++kk)
#pragma unroll
            for (int mi = 0; mi < 2; ++mi)
#pragma unroll
                for (int ni = 0; ni < 4; ++ni)
                    acc[mi][ni] = __builtin_amdgcn_mfma_f32_16x16x32_bf16(fa[kk][mi], fb[kk][ni], acc[mi][ni], 0, 0, 0);
        __builtin_amdgcn_s_setprio(0);
        asm volatile("s_waitcnt lgkmcnt(0)" ::: "memory");       // all ds_reads landed
        __builtin_amdgcn_s_barrier();                            // before buf reuse
    }

    float cm[4] = {0.f, 0.f, 0.f, 0.f};
#pragma unroll
    for (int mi = 0; mi < 2; ++mi)
#pragma unroll
        for (int ni = 0; ni < 4; ++ni) {
            const int col = colT + wn + ni * 16 + l15;
#pragma unroll
            for (int r = 0; r < 4; ++r) {
                const int row = rowT + wm + mi * 16 + quad * 4 + r;
                const float v = acc[mi][ni][r];
                if (z == 0) {
                    if (row < ROWS) qkv16[(size_t)row * QK3 + col] = f2bf(v);
                } else {
                    qkvm16[(size_t)row * QK3 + col] = f2bf(v);
                    cm[ni] = fmaxf(cm[ni], v);
                }
            }
        }
    if (z == 1) {
        const int bb = rowT >> 10;
#pragma unroll
        for (int ni = 0; ni < 4; ++ni) {
            float m = cm[ni];
            m = fmaxf(m, __shfl_xor(m, 16, 64));
            m = fmaxf(m, __shfl_xor(m, 32, 64));
            if (quad == 0)
                atomicMax((int*)&cmax[bb * QK3 + colT + wn + ni * 16 + l15], __float_as_int(m));
        }
    }
}

// ---------------------------------------------------------------------------
// K3: prep in FRAGMENT-MAJOR layout (cvtpk version, unchanged)
// ---------------------------------------------------------------------------
__global__ __launch_bounds__(TPB)
void k_prep(const unsigned short* __restrict__ qkv16,
            const unsigned short* __restrict__ qkvm16,
            const float* __restrict__ cmax, unsigned short* __restrict__ qe,
            unsigned short* __restrict__ kfrag, unsigned short* __restrict__ vfrag)
{
    __shared__ unsigned short Vt_l[128 * 66];
    const int t = threadIdx.x;
    const int nt = blockIdx.x, h = blockIdx.y, b = blockIdx.z;
    const int bh = b * HEADS + h;
    const int nl = t >> 2, ds0 = (t & 3) * 16;
    const int n = nt * 64 + nl;
    const bool valid = n < NTOK;
    const int col0 = h * 64 + ds0;

    unsigned short q16[16] __attribute__((aligned(16))) = {0};
    unsigned short k16[16] __attribute__((aligned(16))) = {0};
    unsigned short v16[16] __attribute__((aligned(16))) = {0};
    unsigned short qm16[16] __attribute__((aligned(16)));
    unsigned short km16[16] __attribute__((aligned(16)));
    unsigned short vm16[16] __attribute__((aligned(16)));
    float cq[16], ck[16], cv[16];

    const bool useM = valid && (n > 0);
    if (valid) {
        const size_t br = (size_t)(b * NTOK + n) * QK3 + col0;
        *(short8*)&q16[0] = *(const short8*)(qkv16 + br);
        *(short8*)&q16[8] = *(const short8*)(qkv16 + br + 8);
        *(short8*)&k16[0] = *(const short8*)(qkv16 + br + 768);
        *(short8*)&k16[8] = *(const short8*)(qkv16 + br + 776);
        *(short8*)&v16[0] = *(const short8*)(qkv16 + br + 1536);
        *(short8*)&v16[8] = *(const short8*)(qkv16 + br + 1544);
    }
    if (useM) {
        const size_t mr = (size_t)(b * 1024 + (n - 1)) * QK3 + col0;
        *(short8*)&qm16[0] = *(const short8*)(qkvm16 + mr);
        *(short8*)&qm16[8] = *(const short8*)(qkvm16 + mr + 8);
        *(short8*)&km16[0] = *(const short8*)(qkvm16 + mr + 768);
        *(short8*)&km16[8] = *(const short8*)(qkvm16 + mr + 776);
        *(short8*)&vm16[0] = *(const short8*)(qkvm16 + mr + 1536);
        *(short8*)&vm16[8] = *(const short8*)(qkvm16 + mr + 1544);
        const int cb = b * QK3 + col0;
#pragma unroll
        for (int i = 0; i < 4; ++i) {
            *(float4*)&cq[i * 4] = *(const float4*)(cmax + cb + i * 4);
            *(float4*)&ck[i * 4] = *(const float4*)(cmax + cb + 768 + i * 4);
            *(float4*)&cv[i * 4] = *(const float4*)(cmax + cb + 1536 + i * 4);
        }
    }

    float fq[16], fk[16];
#pragma unroll
    for (int idx = 0; idx < 16; ++idx) {
        const float qm = useM ? bf2f(qm16[idx]) / (1e-6f + cq[idx]) : 1.f;
        const float km = useM ? bf2f(km16[idx]) / (1e-6f + ck[idx]) : 1.f;
        const float vm = valid ? (useM ? bf2f(vm16[idx]) / (1e-6f + cv[idx]) : 1.f) : 0.f;
        // 0.125 * log2(e): softmax becomes exp2(S' - 10*log2(e))
        fq[idx] = bf2f(q16[idx]) * qm * 0.18033688f;
        fk[idx] = bf2f(k16[idx]) * km;
        const int d = ds0 + idx;
        Vt_l[d * 66 + nl]        = f2bf(bf2f(v16[idx]) * vm);
        Vt_l[(64 + d) * 66 + nl] = f2bf(vm);
    }
    union { unsigned int u[4]; short8 s; } pq0, pq1, pk0, pk1;
#pragma unroll
    for (int i = 0; i < 4; ++i) {
        pq0.u[i] = cvtpk(fq[2 * i],     fq[2 * i + 1]);
        pq1.u[i] = cvtpk(fq[8 + 2 * i], fq[9 + 2 * i]);
        pk0.u[i] = cvtpk(fk[2 * i],     fk[2 * i + 1]);
        pk1.u[i] = cvtpk(fk[8 + 2 * i], fk[9 + 2 * i]);
    }
    // Q: row-major, unconditional (zeros for invalid rows)
    {
        unsigned short* qp = qe + ((size_t)bh * NPAD + n) * 64 + ds0;
        *(short8*)qp       = pq0.s;
        *(short8*)(qp + 8) = pq1.s;
    }
    // K: fragment-major, unconditional
    {
        const int nc = nl >> 4, l15 = nl & 15;
        const int kk = ds0 >> 5, qb = (ds0 & 31) >> 3;   // quads qb, qb+1
        unsigned short* kp = kfrag + (((size_t)bh * 17 + nt) * 8 + kk * 4 + nc) * 512;
        *(short8*)(kp + ((size_t)(qb * 16 + l15)) * 8)       = pk0.s;
        *(short8*)(kp + ((size_t)((qb + 1) * 16 + l15)) * 8) = pk1.s;
    }
    __syncthreads();
    // V^T: fragment-major from the LDS transpose
    const int c = t >> 1, nh = (t & 1) * 32;
    unsigned short ov[32] __attribute__((aligned(16)));
#pragma unroll
    for (int i = 0; i < 32; ++i) ov[i] = Vt_l[c * 66 + nh + i];
    const int c8 = c >> 4, l15v = c & 15, kkv = nh >> 5;
    unsigned short* vp = vfrag + (((size_t)bh * 17 + nt) * 16 + c8 * 2 + kkv) * 512 + (size_t)l15v * 8;
#pragma unroll
    for (int qd = 0; qd < 4; ++qd)
        *(short8*)(vp + (size_t)qd * 128) = *(short8*)(ov + qd * 8);
}

// ---------------------------------------------------------------------------
// K4: MFMA flash attention — 2-q-tile/wave version (grid 33x48 = 1584).
// R9 proved the 2-tile load-amortization IS the optimization. Do not churn.
// ---------------------------------------------------------------------------
__global__ __launch_bounds__(64, 2)
void k_attn(const unsigned short* __restrict__ qe, const unsigned short* __restrict__ kfrag,
            const unsigned short* __restrict__ vfrag, const float* __restrict__ upd,
            unsigned short* __restrict__ ab2)
{
    const int flat = blockIdx.y * 33 + blockIdx.x;
    const int d2 = (flat & 7) * 198 + (flat >> 3);   // 1584 = 8*198, bijective
    const int bh = d2 / 33, qt = d2 - bh * 33;
    const int b = bh / HEADS, h = bh - b * HEADS;
    const int lane = threadIdx.x;
    const int l15 = lane & 15, quad = lane >> 4;
    const int q0 = qt * 32;

    short8 qf[2][2];
#pragma unroll
    for (int j = 0; j < 2; ++j) {
        const unsigned short* qp = qe + ((size_t)bh * NPAD + q0 + j * 16 + l15) * 64 + (quad << 3);
        qf[j][0] = *(const short8*)qp;
        qf[j][1] = *(const short8*)(qp + 32);
    }
    const int pA = (quad & 1) * 32 + l15;
    const int pB = pA + 16;
    const bool lo32 = (lane < 32);

    const unsigned short* kb = kfrag + (size_t)bh * (17 * 8 * 512) + (size_t)lane * 8;
    const unsigned short* vb = vfrag + (size_t)bh * (17 * 16 * 512) + (size_t)lane * 8;

    short8 kf[8], vf[16];
#pragma unroll
    for (int g = 0; g < 8; ++g) kf[g] = *(const short8*)(kb + g * 512);
#pragma unroll
    for (int g = 0; g < 16; ++g) vf[g] = *(const short8*)(vb + g * 512);

    f32x4 acc[2][8];
    float lac[2] = {0.f, 0.f};
#pragma unroll
    for (int j = 0; j < 2; ++j)
#pragma unroll
        for (int g = 0; g < 8; ++g) acc[j][g] = (f32x4){0.f, 0.f, 0.f, 0.f};

    const float EC = 14.4269504f;   // 10*log2(e)

#pragma clang loop unroll(disable)
    for (int kt = 0; kt < 17; ++kt) {
        // S^T (q pre-scaled by 0.125*log2e)
        f32x4 s[2][4];
        __builtin_amdgcn_s_setprio(1);
#pragma unroll
        for (int nc = 0; nc < 4; ++nc) {
#pragma unroll
            for (int j = 0; j < 2; ++j) {
                f32x4 z = (f32x4){0.f, 0.f, 0.f, 0.f};
                z = __builtin_amdgcn_mfma_f32_16x16x32_bf16(kf[nc], qf[j][0], z, 0, 0, 0);
                z = __builtin_amdgcn_mfma_f32_16x16x32_bf16(kf[4 + nc], qf[j][1], z, 0, 0, 0);
                s[j][nc] = z;
            }
        }
        __builtin_amdgcn_s_setprio(0);
        // prefetch next K tile
        if (kt < 16) {
            const unsigned short* kn = kb + (size_t)(kt + 1) * 4096;
#pragma unroll
            for (int g = 0; g < 8; ++g) kf[g] = *(const short8*)(kn + g * 512);
        }
        // p = exp2(S' - EC); pack via v_cvt_pk_bf16_f32; accumulate l in-register
        short8 pf[2][2];
#pragma unroll
        for (int j = 0; j < 2; ++j) {
            unsigned int dA[4], dB[4];
            float psum = 0.f, p00 = 0.f;
#pragma unroll
            for (int nc = 0; nc < 4; ++nc) {
                const float p0 = __builtin_amdgcn_exp2f(s[j][nc][0] - EC);
                const float p1 = __builtin_amdgcn_exp2f(s[j][nc][1] - EC);
                const float p2 = __builtin_amdgcn_exp2f(s[j][nc][2] - EC);
                const float p3 = __builtin_amdgcn_exp2f(s[j][nc][3] - EC);
                dA[nc] = cvtpk(p0, p1);
                dB[nc] = cvtpk(p2, p3);
                psum += (p0 + p1) + (p2 + p3);
                if (nc == 0) p00 = p0;
            }
            if (kt < 16) lac[j] += psum;          // all 64 rows valid
            else if (quad == 0) lac[j] += p00;    // only n==1024 valid in last tile
            union { int i[4]; short8 s; } u0, u1;
            {
                const int a0 = __shfl((int)dA[0], pA, 64), a1 = __shfl((int)dA[1], pA, 64);
                const int b0 = __shfl((int)dB[0], pA, 64), b1 = __shfl((int)dB[1], pA, 64);
                const int a2 = __shfl((int)dA[0], pB, 64), a3 = __shfl((int)dA[1], pB, 64);
                const int b2 = __shfl((int)dB[0], pB, 64), b3 = __shfl((int)dB[1], pB, 64);
                u0.i[0] = lo32 ? a0 : a1;
                u0.i[1] = lo32 ? b0 : b1;
                u0.i[2] = lo32 ? a2 : a3;
                u0.i[3] = lo32 ? b2 : b3;
            }
            {
                const int a0 = __shfl((int)dA[2], pA, 64), a1 = __shfl((int)dA[3], pA, 64);
                const int b0 = __shfl((int)dB[2], pA, 64), b1 = __shfl((int)dB[3], pA, 64);
                const int a2 = __shfl((int)dA[2], pB, 64), a3 = __shfl((int)dA[3], pB, 64);
                const int b2 = __shfl((int)dB[2], pB, 64), b3 = __shfl((int)dB[3], pB, 64);
                u1.i[0] = lo32 ? a0 : a1;
                u1.i[1] = lo32 ? b0 : b1;
                u1.i[2] = lo32 ? a2 : a3;
                u1.i[3] = lo32 ? b2 : b3;
            }
            pf[j][0] = u0.s;
            pf[j][1] = u1.s;
        }
        // O^T += V^T P^T
        __builtin_amdgcn_s_setprio(1);
#pragma unroll
        for (int g = 0; g < 8; ++g) {
#pragma unroll
            for (int j = 0; j < 2; ++j) {
                acc[j][g] = __builtin_amdgcn_mfma_f32_16x16x32_bf16(vf[2 * g],     pf[j][0], acc[j][g], 0, 0, 0);
                acc[j][g] = __builtin_amdgcn_mfma_f32_16x16x32_bf16(vf[2 * g + 1], pf[j][1], acc[j][g], 0, 0, 0);
            }
        }
        __builtin_amdgcn_s_setprio(0);
        // prefetch next V tile
        if (kt < 16) {
            const unsigned short* vn = vb + (size_t)(kt + 1) * 8192;
#pragma unroll
            for (int g = 0; g < 16; ++g) vf[g] = *(const short8*)(vn + g * 512);
        }
    }

#pragma unroll
    for (int j = 0; j < 2; ++j) {
        float lq = lac[j];
        lq += __shfl_xor(lq, 16, 64);
        lq += __shfl_xor(lq, 32, 64);   // every lane now holds l for q = l15
        const int qrow = q0 + j * 16 + l15;
        if (qrow < NTOK) {
            const size_t rg = (size_t)b * NTOK + qrow;
            const float inv = upd[rg] / lq;
#pragma unroll
            for (int g = 0; g < 8; ++g) {
                uint2 pk;
                pk.x = cvtpk(acc[j][g][0] * inv, acc[j][g][1] * inv);
                pk.y = cvtpk(acc[j][g][2] * inv, acc[j][g][3] * inv);
                const size_t addr = (size_t)(g >> 2) * APLANE + rg * DIM + h * 64 + (g & 3) * 16 + quad * 4;
                *(uint2*)(ab2 + addr) = pk;
            }
        }
    }
}

// ---------------------------------------------------------------------------
// K5: bf16 MFMA out-GEMMs — R11 8-wave BK=64 version (best measured).
// ---------------------------------------------------------------------------
__global__ __launch_bounds__(512)
void k_gemm_out_mfma(const unsigned short* __restrict__ ab2,
                     const unsigned short* __restrict__ Wo,
                     const float* __restrict__ bout, float* __restrict__ dout)
{
    const int bid = blockIdx.x;
    const int xcd = bid & 7, rr = bid >> 3;
    const int id = (xcd < 4) ? (xcd * 50 + rr) : (200 + (xcd - 4) * 49 + rr);
    const int z = id / 198;
    const int rem = id - z * 198;
    const int by = rem / 6, bx = rem - by * 6;
    const int rowT = by * 128, colT = bx * 128;

    const unsigned short* A = ab2 + (size_t)z * APLANE;
    const unsigned short* B = Wo + (size_t)z * DIM * DIM;

    __shared__ unsigned short As[2][128 * 64];
    __shared__ unsigned short Bs[2][128 * 64];

    const int t = threadIdx.x;                   // 0..511
    const int w = t >> 6, lane = t & 63, l15 = lane & 15, quad = lane >> 4;
    const int wm = (w & 3) * 32, wn = (w >> 2) * 64;

    auto stage = [&](int buf, int k0) {
#pragma unroll
        for (int p = 0; p < 2; ++p) {
            const int i = p * 512 + t;
            const int row = i >> 3, ch = i & 7;
            const int gc = k0 + ((ch ^ (row & 7)) << 3);
            gl_lds16(A + (size_t)(rowT + row) * DIM + gc, As[buf] + (size_t)i * 8);
            gl_lds16(B + (size_t)(colT + row) * DIM + gc, Bs[buf] + (size_t)i * 8);
        }
    };

    f32x4 acc[2][4];
#pragma unroll
    for (int i = 0; i < 2; ++i)
#pragma unroll
        for (int j = 0; j < 4; ++j) acc[i][j] = (f32x4){0.f, 0.f, 0.f, 0.f};

    stage(0, 0);
#pragma clang loop unroll(disable)
    for (int kt = 0; kt < 12; ++kt) {
        const int cur = kt & 1;
        if (kt < 11) {
            stage(cur ^ 1, (kt + 1) * 64);
            asm volatile("s_waitcnt vmcnt(4)" ::: "memory");
        } else {
            asm volatile("s_waitcnt vmcnt(0)" ::: "memory");
        }
        __builtin_amdgcn_s_barrier();
        __builtin_amdgcn_sched_barrier(0);
        const unsigned short* as = As[cur];
        const unsigned short* bs = Bs[cur];
        short8 fa[2][2], fb[2][4];
#pragma unroll
        for (int kk = 0; kk < 2; ++kk) {
            const int rc = ((kk * 4 + quad) ^ (l15 & 7)) << 3;
#pragma unroll
            for (int mi = 0; mi < 2; ++mi)
                fa[kk][mi] = *(const short8*)(as + (wm + mi * 16 + l15) * 64 + rc);
#pragma unroll
            for (int ni = 0; ni < 4; ++ni)
                fb[kk][ni] = *(const short8*)(bs + (wn + ni * 16 + l15) * 64 + rc);
        }
        __builtin_amdgcn_s_setprio(1);
#pragma unroll
        for (int kk = 0; kk < 2; ++kk)
#pragma unroll
            for (int mi = 0; mi < 2; ++mi)
#pragma unroll
                for (int ni = 0; ni < 4; ++ni)
                    acc[mi][ni] = __builtin_amdgcn_mfma_f32_16x16x32_bf16(fa[kk][mi], fb[kk][ni], acc[mi][ni], 0, 0, 0);
        __builtin_amdgcn_s_setprio(0);
        asm volatile("s_waitcnt lgkmcnt(0)" ::: "memory");
        __builtin_amdgcn_s_barrier();
    }

#pragma unroll
    for (int mi = 0; mi < 2; ++mi)
#pragma unroll
        for (int ni = 0; ni < 4; ++ni) {
            const int col = colT + wn + ni * 16 + l15;
            const float bb = (z == 0) ? bout[col] : 0.f;
#pragma unroll
            for (int r = 0; r < 4; ++r) {
                const int row = rowT + wm + mi * 16 + quad * 4 + r;
                if (row >= ROWS) continue;
                const int b = row / NTOK, n = row % NTOK;
                if (z == 0) {
                    dout[(size_t)row * DIM + col] = acc[mi][ni][r] + bb;
                } else if (n >= 1) {
                    dout[OUT0 + ((size_t)(b * (NTOK - 1) + (n - 1))) * DIM + col] = acc[mi][ni][r];
                }
            }
        }
}

extern "C" void kernel_launch(void* const* d_in, const int* in_sizes, int n_in,
                              void* d_out, int out_size, void* d_ws, size_t ws_size,
                              hipStream_t stream)
{
    const float* x    = (const float*)d_in[0];
    const float* mask = (const float*)d_in[1];
    const float* wqkv = (const float*)d_in[2];
    const float* wout = (const float*)d_in[3];
    const float* bout = (const float*)d_in[4];
    float* ws = (float*)d_ws;
    unsigned short* qkv16  = (unsigned short*)(ws + OFF_QKV16);
    unsigned short* qkvm16 = (unsigned short*)(ws + OFF_QKVM16);
    unsigned short* qe  = (unsigned short*)(ws + OFF_QE);
    unsigned short* kfr = (unsigned short*)(ws + OFF_KF);
    unsigned short* vfr = (unsigned short*)(ws + OFF_VF);
    unsigned short* abf = (unsigned short*)(ws + OFF_ABF);
    unsigned short* wq  = (unsigned short*)(ws + OFF_WQ);
    unsigned short* wo  = (unsigned short*)(ws + OFF_WO);
    float* cmax = ws + OFF_CMAX;
    float* upd  = ws + OFF_UPD;
    float* out  = (float*)d_out;

    hipMemsetAsync(upd, 0, ROWS * sizeof(float), stream);
    hipLaunchKernelGGL(k_cvt,           dim3(1584, 1, 5), dim3(TPB), 0, stream, x, mask, wqkv, wout, abf, wq, wo, upd, cmax);
    hipLaunchKernelGGL(k_gemm_qkv_mfma, dim3(1188),       dim3(512), 0, stream, abf, wq, qkv16, qkvm16, cmax);
    hipLaunchKernelGGL(k_prep,          dim3(17, 12, 4),  dim3(TPB), 0, stream, qkv16, qkvm16, cmax, qe, kfr, vfr);
    hipLaunchKernelGGL(k_attn,          dim3(33, 48),     dim3(64),  0, stream, qe, kfr, vfr, upd, abf);
    hipLaunchKernelGGL(k_gemm_out_mfma, dim3(396),        dim3(512), 0, stream, abf, wo, bout, out);
}